// Round 1
// baseline (243.997 us; speedup 1.0000x reference)
//
#include <hip/hip_runtime.h>
#include <math.h>

// CTC loss, T=1024 B=64 V=256 L=256 (S=513).
// One WAVE per batch element, zero barriers, fully-static register pipeline.
// Round 7: the 345 cyc/step was stall, not issue. Two sources removed:
//  1) LDS round-trip (ds_write_b128 + 5 random ds_read gathers, 1.15M bank-
//     conflict cycles, in-order lgkm drains). Gather indices are FIXED per
//     lane for all t, so each lane now loads its 5 needed logits DIRECTLY
//     from global (SGPR row base + invariant voffsets) into a 4-deep
//     named-register ring (literal slots -> stays in VGPRs). Rows are
//     L2/L3-resident (lse waves stream the same bytes; 67MB < 256MB L3).
//  2) RENORM's 6 serial ds_permute shfl_xor (~380 cyc dead every 16 steps)
//     -> pure-VALU wave reduce: DPP quad_perm/row_ror + gfx950
//     v_permlane16/32_swap (~60 cyc). Same for lse waves' max/sum reduces.
//  - lane l holds states 8l..8l+7; state 512 rides curT, valid on lane 63.
//  - LINEAR-domain recursion on RAW logits (softmax denom deferred to lse).
//  - Renorm every 16 steps; accounting uses APPLIED multiplier.
//  - lse: wave w owns rows r = w + 1024k, writes partial[w]; no atomics.

constexpr int V = 256;
constexpr float LN2_F = 0.6931471805599453f;

typedef unsigned uint2v __attribute__((ext_vector_type(2)));

template <int CTRL>
__device__ __forceinline__ float dpp_mov_f(float x) {
    return __int_as_float(__builtin_amdgcn_update_dpp(
        0, __float_as_int(x), CTRL, 0xF, 0xF, true));
}

// full-wave max/sum in pure VALU: xor1,xor2 (quad_perm), ror4,ror8 (row),
// then cross-16 / cross-32 via permlane swaps (VALU on gfx950).
__device__ __forceinline__ float wave_max_f(float m) {
    m = fmaxf(m, dpp_mov_f<0xB1>(m));    // quad_perm [1,0,3,2] : xor1
    m = fmaxf(m, dpp_mov_f<0x4E>(m));    // quad_perm [2,3,0,1] : xor2
    m = fmaxf(m, dpp_mov_f<0x124>(m));   // row_ror:4
    m = fmaxf(m, dpp_mov_f<0x128>(m));   // row_ror:8
#if __has_builtin(__builtin_amdgcn_permlane16_swap) && __has_builtin(__builtin_amdgcn_permlane32_swap)
    uint2v a = __builtin_amdgcn_permlane16_swap(__float_as_uint(m),
                                                __float_as_uint(m), false, false);
    m = fmaxf(__uint_as_float(a.x), __uint_as_float(a.y));
    uint2v b = __builtin_amdgcn_permlane32_swap(__float_as_uint(m),
                                                __float_as_uint(m), false, false);
    m = fmaxf(__uint_as_float(b.x), __uint_as_float(b.y));
#else
    m = fmaxf(m, __shfl_xor(m, 16, 64));
    m = fmaxf(m, __shfl_xor(m, 32, 64));
#endif
    return m;
}

__device__ __forceinline__ float wave_sum_f(float s) {
    s += dpp_mov_f<0xB1>(s);
    s += dpp_mov_f<0x4E>(s);
    s += dpp_mov_f<0x124>(s);
    s += dpp_mov_f<0x128>(s);
#if __has_builtin(__builtin_amdgcn_permlane16_swap) && __has_builtin(__builtin_amdgcn_permlane32_swap)
    uint2v a = __builtin_amdgcn_permlane16_swap(__float_as_uint(s),
                                                __float_as_uint(s), false, false);
    s = __uint_as_float(a.x) + __uint_as_float(a.y);
    uint2v b = __builtin_amdgcn_permlane32_swap(__float_as_uint(s),
                                                __float_as_uint(s), false, false);
    s = __uint_as_float(b.x) + __uint_as_float(b.y);
#else
    s += __shfl_xor(s, 16, 64);
    s += __shfl_xor(s, 32, 64);
#endif
    return s;
}

#define MACS(EB, E1, E3, E5, E7) do {                                  \
    float c7m = __shfl_up(cur7, 1); c7m = (l == 0) ? 0.f : c7m;        \
    curT = (curT + cur7) * (EB);                                       \
    cur7 = fmaf(sk7, cur5, cur7 + cur6) * (E7);                        \
    cur6 = (cur6 + cur5) * (EB);                                       \
    cur5 = fmaf(sk5, cur3, cur5 + cur4) * (E5);                        \
    cur4 = (cur4 + cur3) * (EB);                                       \
    cur3 = fmaf(sk3, cur1, cur3 + cur2) * (E3);                        \
    cur2 = (cur2 + cur1) * (EB);                                       \
    cur1 = fmaf(sk1, c7m, cur1 + cur0) * (E1);                         \
    cur0 = (cur0 + c7m) * (EB);                                        \
  } while (0)

// one time step: TT = t (expression), SL = literal ring slot == TT&3.
// exp the slot's 5 raw values (loaded 4 steps ago -> vmcnt slack ~4 steps),
// refill the slot with row TT+4 (WAR on regs: exp reads precede load issue),
// then advance the recursion.
#define STEP(TT, SL) do {                                              \
    const float _eb = __expf(rb##SL);                                  \
    const float _e1 = __expf(rx##SL);                                  \
    const float _e3 = __expf(ry##SL);                                  \
    const float _e5 = __expf(rz##SL);                                  \
    const float _e7 = __expf(rw##SL);                                  \
    int _rn = (TT) + 4; if (_rn > Tbm1) _rn = Tbm1;                    \
    const float* _p = lg + rs * (size_t)_rn;                           \
    rb##SL = _p[0];  rx##SL = _p[ix];  ry##SL = _p[iy];                \
    rz##SL = _p[iz]; rw##SL = _p[iw];                                  \
    MACS(_eb, _e1, _e3, _e5, _e7);                                     \
  } while (0)

#define RENORM do {                                                    \
    curT *= mkT; cur0 *= mk0; cur1 *= mk1; cur2 *= mk2; cur3 *= mk3;   \
    cur4 *= mk4; cur5 *= mk5; cur6 *= mk6; cur7 *= mk7;                \
    float _m = fmaxf(curT, cur0); _m = fmaxf(_m, cur1);                \
    _m = fmaxf(_m, cur2); _m = fmaxf(_m, cur3); _m = fmaxf(_m, cur4);  \
    _m = fmaxf(_m, cur5); _m = fmaxf(_m, cur6); _m = fmaxf(_m, cur7);  \
    _m = wave_max_f(_m);                                               \
    const float _inv = 1.f / fmaxf(_m, 1e-30f);                        \
    log2acc -= log2f(_inv);                                            \
    curT *= _inv; cur0 *= _inv; cur1 *= _inv; cur2 *= _inv;            \
    cur3 *= _inv; cur4 *= _inv; cur5 *= _inv; cur6 *= _inv;            \
    cur7 *= _inv;                                                      \
  } while (0)

__global__ __launch_bounds__(64) void ctc_main(
    const int*   __restrict__ labels,      // [B, L]
    const float* __restrict__ logits,      // [T, B, V]
    const int*   __restrict__ label_len,   // [B]
    const int*   __restrict__ logit_len,   // [B]
    float*       __restrict__ partial,     // [nLse] per-wave lse sums
    float*       __restrict__ lnterm,      // [B]
    int T, int B, int L)
{
    const int l = threadIdx.x;             // lane == thread

    if ((int)blockIdx.x < B) {
        // =============== recursion: one wave, one batch element ==============
        __builtin_amdgcn_s_setprio(1);     // latency-critical wave: win issue
                                           // arbitration vs co-resident lse
        const int b = blockIdx.x;
        __shared__ float afin[514];        // final alpha for readout

        const int Tb = logit_len[b];
        const int Lb = label_len[b];
        const int Sb = 2 * Lb + 1;
        const int Tbm1 = Tb - 1;

        const float* lg = logits + (size_t)b * V;
        const size_t rs = (size_t)B * V;

        const int4 lb4 = ((const int4*)(labels + (size_t)b * L))[l];
        const int ix = lb4.x, iy = lb4.y, iz = lb4.z, iw = lb4.w;
        const int prevw = __shfl_up(iw, 1);              // labels[4l-1]
        const float sk1 = (l > 0 && ix != prevw) ? 1.f : 0.f;
        const float sk3 = (iy != ix) ? 1.f : 0.f;
        const float sk5 = (iz != iy) ? 1.f : 0.f;
        const float sk7 = (iw != iz) ? 1.f : 0.f;

        const float mk0 = (8 * l + 0 < Sb) ? 1.f : 0.f;
        const float mk1 = (8 * l + 1 < Sb) ? 1.f : 0.f;
        const float mk2 = (8 * l + 2 < Sb) ? 1.f : 0.f;
        const float mk3 = (8 * l + 3 < Sb) ? 1.f : 0.f;
        const float mk4 = (8 * l + 4 < Sb) ? 1.f : 0.f;
        const float mk5 = (8 * l + 5 < Sb) ? 1.f : 0.f;
        const float mk6 = (8 * l + 6 < Sb) ? 1.f : 0.f;
        const float mk7 = (8 * l + 7 < Sb) ? 1.f : 0.f;
        const float mkT = (Sb > 512 && l == 63) ? 1.f : 0.f;

        // t=0 init: states 0,1 only
        float cur0 = 0.f, cur1 = 0.f, cur2 = 0.f, cur3 = 0.f;
        float cur4 = 0.f, cur5 = 0.f, cur6 = 0.f, cur7 = 0.f, curT = 0.f;
        if (l == 0) {
            cur0 = __expf(lg[0]);
            cur1 = __expf(lg[ix]) * mk1;
        }

        // raw gather ring: slot k holds {blank, ix, iy, iz, iw} logits of a
        // row; slot for step t is t&3, refilled with row t+4 (4-step slack).
        float rb0, rx0, ry0, rz0, rw0;
        float rb1, rx1, ry1, rz1, rw1;
        float rb2, rx2, ry2, rz2, rw2;
        float rb3, rx3, ry3, rz3, rw3;
        {
            int r = (1 <= Tbm1) ? 1 : Tbm1;
            const float* p = lg + rs * (size_t)r;
            rb1 = p[0]; rx1 = p[ix]; ry1 = p[iy]; rz1 = p[iz]; rw1 = p[iw];
            r = (2 <= Tbm1) ? 2 : Tbm1; p = lg + rs * (size_t)r;
            rb2 = p[0]; rx2 = p[ix]; ry2 = p[iy]; rz2 = p[iz]; rw2 = p[iw];
            r = (3 <= Tbm1) ? 3 : Tbm1; p = lg + rs * (size_t)r;
            rb3 = p[0]; rx3 = p[ix]; ry3 = p[iy]; rz3 = p[iz]; rw3 = p[iw];
            r = (4 <= Tbm1) ? 4 : Tbm1; p = lg + rs * (size_t)r;
            rb0 = p[0]; rx0 = p[ix]; ry0 = p[iy]; rz0 = p[iz]; rw0 = p[iw];
        }

        float log2acc = 0.f;
        int base = 1;
        if (Tb >= 16) {
            // first window: t = 1..15
            STEP(1, 1);  STEP(2, 2);  STEP(3, 3);  STEP(4, 0);
            STEP(5, 1);  STEP(6, 2);  STEP(7, 3);  STEP(8, 0);
            STEP(9, 1);  STEP(10, 2); STEP(11, 3); STEP(12, 0);
            STEP(13, 1); STEP(14, 2); STEP(15, 3);
            RENORM;
            // main windows: base ≡ 0 mod 16 -> slot of step base+k is k&3
            for (base = 16; base + 16 <= Tb; base += 16) {
                STEP(base + 0, 0);  STEP(base + 1, 1);
                STEP(base + 2, 2);  STEP(base + 3, 3);
                STEP(base + 4, 0);  STEP(base + 5, 1);
                STEP(base + 6, 2);  STEP(base + 7, 3);
                STEP(base + 8, 0);  STEP(base + 9, 1);
                STEP(base + 10, 2); STEP(base + 11, 3);
                STEP(base + 12, 0); STEP(base + 13, 1);
                STEP(base + 14, 2); STEP(base + 15, 3);
                RENORM;
            }
        }
        // scalar tail (t = base..Tb-1): direct global gathers; <=15 steps of
        // growth cannot overflow, and readout never touches garbage states.
        for (int t = base; t < Tb; ++t) {
            const float* rowp = lg + rs * (size_t)t;
            const float eb = __expf(rowp[0]);
            const float e1 = __expf(rowp[ix]), e3 = __expf(rowp[iy]);
            const float e5 = __expf(rowp[iz]), e7 = __expf(rowp[iw]);
            MACS(eb, e1, e3, e5, e7);
        }

        // readout: ln(a[end] + a[end-1]) + ln2*log2acc
        afin[8 * l + 0] = cur0; afin[8 * l + 1] = cur1;
        afin[8 * l + 2] = cur2; afin[8 * l + 3] = cur3;
        afin[8 * l + 4] = cur4; afin[8 * l + 5] = cur5;
        afin[8 * l + 6] = cur6; afin[8 * l + 7] = cur7;
        if (l == 63) afin[512] = curT;
        const int end = 2 * Lb;
        const int em1 = (end > 0) ? end - 1 : 0;
        float ssum = afin[end] + afin[em1];     // same-wave DS, in-order
        ssum = fmaxf(ssum, 1e-37f);             // inf-protection only
        if (l == 0) lnterm[b] = logf(ssum) + LN2_F * log2acc;
    } else {
        // ====== lse waves: partial[w] = sum of lse over rows r ≡ w (mod nW) ==
        const int w  = blockIdx.x - B;          // 0..nW-1
        const int nW = gridDim.x - B;
        const int rows = T * B;
        const int bb = w % B;                   // constant per wave
        const int Tbb = logit_len[bb];
        float acc = 0.f;
        int r = w;
        if (r < rows) {
            // t = r/B advances by nW/B per iter (nW chosen as a multiple of B)
            int t = w / B;
            const int ts = nW / B;
            float4 nxt = ((const float4*)(logits + (size_t)r * V))[l];
            while (true) {
                const int rn = r + nW;
                const bool more = rn < rows;
                const float4 x = nxt;
                if (more) nxt = ((const float4*)(logits + (size_t)rn * V))[l];
                float m = fmaxf(fmaxf(x.x, x.y), fmaxf(x.z, x.w));
                m = wave_max_f(m);              // pure-VALU 64-lane reduce
                float ss = __expf(x.x - m) + __expf(x.y - m) +
                           __expf(x.z - m) + __expf(x.w - m);
                ss = wave_sum_f(ss);
                if (t < Tbb) acc += m + logf(ss);
                if (!more) break;
                r = rn; t += ts;
            }
        }
        if (l == 0) partial[w] = acc;
    }
}

__global__ __launch_bounds__(64) void ctc_final(
    const float* __restrict__ partial,     // [nW]
    const float* __restrict__ lnterm,      // [B]
    float* __restrict__ out, int B, int nW)
{
    const int b = threadIdx.x;
    float v = 0.f;
    if (b < B) {
        float c = 0.f;
        for (int k = b; k < nW; k += B) c += partial[k];
        v = c - lnterm[b];
    }
    #pragma unroll
    for (int o = 32; o >= 1; o >>= 1) v += __shfl_xor(v, o, 64);
    if (threadIdx.x == 0) out[0] = v / (float)B;
}

extern "C" void kernel_launch(void* const* d_in, const int* in_sizes, int n_in,
                              void* d_out, int out_size, void* d_ws, size_t ws_size,
                              hipStream_t stream) {
    const int*   labels    = (const int*)d_in[0];
    const float* logits    = (const float*)d_in[1];
    const int*   label_len = (const int*)d_in[2];
    const int*   logit_len = (const int*)d_in[3];

    const int B = in_sizes[2];                 // 64
    const int L = in_sizes[0] / B;             // 256
    const int T = in_sizes[1] / (B * V);       // 1024

    const int nLse = 1024;                     // 64 rows per lse wave; %B==0
    float* partial = (float*)d_ws;             // [nLse]
    float* lnterm  = partial + nLse;           // [B]

    ctc_main<<<B + nLse, 64, 0, stream>>>(labels, logits, label_len, logit_len,
                                          partial, lnterm, T, B, L);
    ctc_final<<<1, 64, 0, stream>>>(partial, lnterm, (float*)d_out, B, nLse);
}

// Round 2
// 210.726 us; speedup vs baseline: 1.1579x; 1.1579x over previous
//
#include <hip/hip_runtime.h>
#include <math.h>

// CTC loss, T=1024 B=64 V=256 L=256 (S=513).
// One WAVE per batch element, zero barriers, fully-static register pipeline.
// Round 8: round-7 post-mortem showed the per-step global scatter (5 loads,
// ~80 VMEM txns/step) was WORSE than the LDS path: memory pipe serialized at
// ~385 cyc/step with zero TLP. Revert to round-6's coalesced-row LDS staging.
// The REAL round-6 bottleneck was the per-step ds_permute (__shfl_up): DS ops
// complete in order, so consuming the permute result every step drained the
// 6 staged DS ops (write_b128 + 5 gathers) and destroyed the 2-step slack.
// This version moves the cross-lane hop onto the VALU: DPP wave_shr:1
// (ctrl 0x138, bound_ctrl=1 -> lane0 reads 0), a ~2-cyc op. No per-step DS
// consumption remains, so staging slack is real and the compiler can use
// counted lgkm waits.
//  - lane l holds states 8l..8l+7; state 512 rides curT, valid on lane 63.
//  - LINEAR-domain recursion on RAW logits (softmax denom deferred to lse).
//  - Pipeline at step t: consume gather-set g[t&3] (EXP'D row-t values);
//    stage row t+2 (4 exps on ring regs -> ds_write_b128 -> 5 gathers into
//    g[(t+2)&3]); refill ring slot (t+2)&3 with row t+6. 2-step DS slack,
//    4-step global slack, no vmcnt(0)/lgkmcnt(0) drains anywhere.
//  - Renorm every 16 steps (worst-case growth ~2^106 < 2^127); pure-VALU
//    DPP + permlane16/32_swap wave reduce (no DS ops).
//  - lse: wave w owns rows r = w + 1024k, writes partial[w]; DPP reduces.

constexpr int V = 256;
constexpr float LN2_F = 0.6931471805599453f;

typedef unsigned uint2v __attribute__((ext_vector_type(2)));

template <int CTRL>
__device__ __forceinline__ float dpp_mov_f(float x) {
    return __int_as_float(__builtin_amdgcn_update_dpp(
        0, __float_as_int(x), CTRL, 0xF, 0xF, true));
}

// whole-wave shift down by 1 lane (lane l reads lane l-1; lane 0 -> 0).
// VALU op: replaces ds_permute shfl_up + the l==0 cndmask.
__device__ __forceinline__ float wave_shr1_f(float x) {
    return __int_as_float(__builtin_amdgcn_update_dpp(
        0, __float_as_int(x), 0x138, 0xF, 0xF, true));  // wave_shr:1
}

// full-wave max/sum in pure VALU: xor1,xor2 (quad_perm), ror4,ror8 (row),
// then cross-16 / cross-32 via permlane swaps (VALU on gfx950).
__device__ __forceinline__ float wave_max_f(float m) {
    m = fmaxf(m, dpp_mov_f<0xB1>(m));    // quad_perm [1,0,3,2] : xor1
    m = fmaxf(m, dpp_mov_f<0x4E>(m));    // quad_perm [2,3,0,1] : xor2
    m = fmaxf(m, dpp_mov_f<0x124>(m));   // row_ror:4
    m = fmaxf(m, dpp_mov_f<0x128>(m));   // row_ror:8
#if __has_builtin(__builtin_amdgcn_permlane16_swap) && __has_builtin(__builtin_amdgcn_permlane32_swap)
    uint2v a = __builtin_amdgcn_permlane16_swap(__float_as_uint(m),
                                                __float_as_uint(m), false, false);
    m = fmaxf(__uint_as_float(a.x), __uint_as_float(a.y));
    uint2v b = __builtin_amdgcn_permlane32_swap(__float_as_uint(m),
                                                __float_as_uint(m), false, false);
    m = fmaxf(__uint_as_float(b.x), __uint_as_float(b.y));
#else
    m = fmaxf(m, __shfl_xor(m, 16, 64));
    m = fmaxf(m, __shfl_xor(m, 32, 64));
#endif
    return m;
}

__device__ __forceinline__ float wave_sum_f(float s) {
    s += dpp_mov_f<0xB1>(s);
    s += dpp_mov_f<0x4E>(s);
    s += dpp_mov_f<0x124>(s);
    s += dpp_mov_f<0x128>(s);
#if __has_builtin(__builtin_amdgcn_permlane16_swap) && __has_builtin(__builtin_amdgcn_permlane32_swap)
    uint2v a = __builtin_amdgcn_permlane16_swap(__float_as_uint(s),
                                                __float_as_uint(s), false, false);
    s = __uint_as_float(a.x) + __uint_as_float(a.y);
    uint2v b = __builtin_amdgcn_permlane32_swap(__float_as_uint(s),
                                                __float_as_uint(s), false, false);
    s = __uint_as_float(b.x) + __uint_as_float(b.y);
#else
    s += __shfl_xor(s, 16, 64);
    s += __shfl_xor(s, 32, 64);
#endif
    return s;
}

#define MACS(EB, E1, E3, E5, E7) do {                                  \
    const float c7m = wave_shr1_f(cur7);   /* VALU, no DS queue */     \
    curT = (curT + cur7) * (EB);                                       \
    cur7 = fmaf(sk7, cur5, cur7 + cur6) * (E7);                        \
    cur6 = (cur6 + cur5) * (EB);                                       \
    cur5 = fmaf(sk5, cur3, cur5 + cur4) * (E5);                        \
    cur4 = (cur4 + cur3) * (EB);                                       \
    cur3 = fmaf(sk3, cur1, cur3 + cur2) * (E3);                        \
    cur2 = (cur2 + cur1) * (EB);                                       \
    cur1 = fmaf(sk1, c7m, cur1 + cur0) * (E1);                         \
    cur0 = (cur0 + c7m) * (EB);                                        \
  } while (0)

// exp the ring regs, write exp'd row to LDS, gather 5 values into set GS
#define STAGE_GATHER(GS, XV) do {                                      \
    float4 _e;                                                         \
    _e.x = __expf((XV).x); _e.y = __expf((XV).y);                      \
    _e.z = __expf((XV).z); _e.w = __expf((XV).w);                      \
    ((float4*)erow)[l] = _e;                                           \
    GS##b = erow[0];  GS##p = erow[ix]; GS##q = erow[iy];              \
    GS##r = erow[iz]; GS##s = erow[iw];                                \
  } while (0)

// one time step: TT = t (expression), GC/GS = gather-set name tokens,
// SL = literal ring slot == (t+2)&3
#define STEP(TT, GC, GS, SL) do {                                      \
    MACS(GC##b, GC##p, GC##q, GC##r, GC##s);                           \
    float4 _x = rp##SL;                                                \
    STAGE_GATHER(GS, _x);                                              \
    int _rn = (TT) + 6; if (_rn > Tbm1) _rn = Tbm1;                    \
    rp##SL = *(const float4*)(lg + rs * (size_t)_rn + 4 * l);          \
  } while (0)

#define RENORM do {                                                    \
    curT *= mkT; cur0 *= mk0; cur1 *= mk1; cur2 *= mk2; cur3 *= mk3;   \
    cur4 *= mk4; cur5 *= mk5; cur6 *= mk6; cur7 *= mk7;                \
    float _m = fmaxf(curT, cur0); _m = fmaxf(_m, cur1);                \
    _m = fmaxf(_m, cur2); _m = fmaxf(_m, cur3); _m = fmaxf(_m, cur4);  \
    _m = fmaxf(_m, cur5); _m = fmaxf(_m, cur6); _m = fmaxf(_m, cur7);  \
    _m = wave_max_f(_m);                                               \
    const float _inv = 1.f / fmaxf(_m, 1e-30f);                        \
    log2acc -= log2f(_inv);                                            \
    curT *= _inv; cur0 *= _inv; cur1 *= _inv; cur2 *= _inv;            \
    cur3 *= _inv; cur4 *= _inv; cur5 *= _inv; cur6 *= _inv;            \
    cur7 *= _inv;                                                      \
  } while (0)

__global__ __launch_bounds__(64) void ctc_main(
    const int*   __restrict__ labels,      // [B, L]
    const float* __restrict__ logits,      // [T, B, V]
    const int*   __restrict__ label_len,   // [B]
    const int*   __restrict__ logit_len,   // [B]
    float*       __restrict__ partial,     // [nLse] per-wave lse sums
    float*       __restrict__ lnterm,      // [B]
    int T, int B, int L)
{
    const int l = threadIdx.x;             // lane == thread

    if ((int)blockIdx.x < B) {
        // =============== recursion: one wave, one batch element ==============
        __builtin_amdgcn_s_setprio(1);     // latency-critical wave: win issue
                                           // arbitration vs co-resident lse
        const int b = blockIdx.x;
        __shared__ float erow[V];          // exp'd logit row (single buffer:
                                           // same-wave DS ops are in-order)
        __shared__ float afin[514];        // final alpha for readout

        const int Tb = logit_len[b];
        const int Lb = label_len[b];
        const int Sb = 2 * Lb + 1;
        const int Tbm1 = Tb - 1;

        const float* lg = logits + (size_t)b * V;
        const size_t rs = (size_t)B * V;

        const int4 lb4 = ((const int4*)(labels + (size_t)b * L))[l];
        const int ix = lb4.x, iy = lb4.y, iz = lb4.z, iw = lb4.w;
        const int prevw = __shfl_up(iw, 1);              // labels[4l-1], once
        const float sk1 = (l > 0 && ix != prevw) ? 1.f : 0.f;
        const float sk3 = (iy != ix) ? 1.f : 0.f;
        const float sk5 = (iz != iy) ? 1.f : 0.f;
        const float sk7 = (iw != iz) ? 1.f : 0.f;

        const float mk0 = (8 * l + 0 < Sb) ? 1.f : 0.f;
        const float mk1 = (8 * l + 1 < Sb) ? 1.f : 0.f;
        const float mk2 = (8 * l + 2 < Sb) ? 1.f : 0.f;
        const float mk3 = (8 * l + 3 < Sb) ? 1.f : 0.f;
        const float mk4 = (8 * l + 4 < Sb) ? 1.f : 0.f;
        const float mk5 = (8 * l + 5 < Sb) ? 1.f : 0.f;
        const float mk6 = (8 * l + 6 < Sb) ? 1.f : 0.f;
        const float mk7 = (8 * l + 7 < Sb) ? 1.f : 0.f;
        const float mkT = (Sb > 512 && l == 63) ? 1.f : 0.f;

        // t=0 init: states 0,1 only
        float cur0 = 0.f, cur1 = 0.f, cur2 = 0.f, cur3 = 0.f;
        float cur4 = 0.f, cur5 = 0.f, cur6 = 0.f, cur7 = 0.f, curT = 0.f;
        if (l == 0) {
            cur0 = __expf(lg[0]);
            cur1 = __expf(lg[ix]) * mk1;
        }

        // gather sets (5 regs each): g<k> holds exp'd row values, row ≡ k mod 4
        float g0b = 0, g0p = 0, g0q = 0, g0r = 0, g0s = 0;
        float g1b = 0, g1p = 0, g1q = 0, g1r = 0, g1s = 0;
        float g2b = 0, g2p = 0, g2q = 0, g2r = 0, g2s = 0;
        float g3b = 0, g3p = 0, g3q = 0, g3r = 0, g3s = 0;

        // prologue: stage rows 1,2 -> g1,g2
        {
            int r = (1 < Tbm1) ? 1 : Tbm1;
            float4 x = *(const float4*)(lg + rs * (size_t)r + 4 * l);
            STAGE_GATHER(g1, x);
            r = (2 < Tbm1) ? 2 : Tbm1;
            x = *(const float4*)(lg + rs * (size_t)r + 4 * l);
            STAGE_GATHER(g2, x);
        }
        // ring prefill: rp<k> = row k+3 pattern -> rp3=row3, rp0=4, rp1=5, rp2=6
        float4 rp0, rp1, rp2, rp3;
        {
            int r3 = (3 < Tbm1) ? 3 : Tbm1, r4 = (4 < Tbm1) ? 4 : Tbm1;
            int r5 = (5 < Tbm1) ? 5 : Tbm1, r6 = (6 < Tbm1) ? 6 : Tbm1;
            rp3 = *(const float4*)(lg + rs * (size_t)r3 + 4 * l);
            rp0 = *(const float4*)(lg + rs * (size_t)r4 + 4 * l);
            rp1 = *(const float4*)(lg + rs * (size_t)r5 + 4 * l);
            rp2 = *(const float4*)(lg + rs * (size_t)r6 + 4 * l);
        }

        float log2acc = 0.f;
        int base = 1;
        if (Tb >= 16) {
            // first window: t = 1..15
            STEP(1,  g1, g3, 3);  STEP(2,  g2, g0, 0);
            STEP(3,  g3, g1, 1);  STEP(4,  g0, g2, 2);
            STEP(5,  g1, g3, 3);  STEP(6,  g2, g0, 0);
            STEP(7,  g3, g1, 1);  STEP(8,  g0, g2, 2);
            STEP(9,  g1, g3, 3);  STEP(10, g2, g0, 0);
            STEP(11, g3, g1, 1);  STEP(12, g0, g2, 2);
            STEP(13, g1, g3, 3);  STEP(14, g2, g0, 0);
            STEP(15, g3, g1, 1);
            RENORM;
            // main windows: base ≡ 0 mod 16
            for (base = 16; base + 16 <= Tb; base += 16) {
                STEP(base + 0,  g0, g2, 2);  STEP(base + 1,  g1, g3, 3);
                STEP(base + 2,  g2, g0, 0);  STEP(base + 3,  g3, g1, 1);
                STEP(base + 4,  g0, g2, 2);  STEP(base + 5,  g1, g3, 3);
                STEP(base + 6,  g2, g0, 0);  STEP(base + 7,  g3, g1, 1);
                STEP(base + 8,  g0, g2, 2);  STEP(base + 9,  g1, g3, 3);
                STEP(base + 10, g2, g0, 0);  STEP(base + 11, g3, g1, 1);
                STEP(base + 12, g0, g2, 2);  STEP(base + 13, g1, g3, 3);
                STEP(base + 14, g2, g0, 0);  STEP(base + 15, g3, g1, 1);
                RENORM;
            }
        }
        // scalar tail (t = base..Tb-1): direct global gathers; <=15 steps of
        // growth cannot overflow, and readout never touches garbage states.
        for (int t = base; t < Tb; ++t) {
            const float* rowp = lg + rs * (size_t)t;
            const float eb = __expf(rowp[0]);
            const float e1 = __expf(rowp[ix]), e3 = __expf(rowp[iy]);
            const float e5 = __expf(rowp[iz]), e7 = __expf(rowp[iw]);
            MACS(eb, e1, e3, e5, e7);
        }

        // readout: ln(a[end] + a[end-1]) + ln2*log2acc
        afin[8 * l + 0] = cur0; afin[8 * l + 1] = cur1;
        afin[8 * l + 2] = cur2; afin[8 * l + 3] = cur3;
        afin[8 * l + 4] = cur4; afin[8 * l + 5] = cur5;
        afin[8 * l + 6] = cur6; afin[8 * l + 7] = cur7;
        if (l == 63) afin[512] = curT;
        const int end = 2 * Lb;
        const int em1 = (end > 0) ? end - 1 : 0;
        float ssum = afin[end] + afin[em1];     // same-wave DS, in-order
        ssum = fmaxf(ssum, 1e-37f);             // inf-protection only
        if (l == 0) lnterm[b] = logf(ssum) + LN2_F * log2acc;
    } else {
        // ====== lse waves: partial[w] = sum of lse over rows r ≡ w (mod nW) ==
        const int w  = blockIdx.x - B;          // 0..nW-1
        const int nW = gridDim.x - B;
        const int rows = T * B;
        const int bb = w % B;                   // constant per wave
        const int Tbb = logit_len[bb];
        float acc = 0.f;
        int r = w;
        if (r < rows) {
            // t = r/B advances by nW/B per iter (nW is a multiple of B)
            int t = w / B;
            const int ts = nW / B;
            float4 nxt = ((const float4*)(logits + (size_t)r * V))[l];
            while (true) {
                const int rn = r + nW;
                const bool more = rn < rows;
                const float4 x = nxt;
                if (more) nxt = ((const float4*)(logits + (size_t)rn * V))[l];
                float m = fmaxf(fmaxf(x.x, x.y), fmaxf(x.z, x.w));
                m = wave_max_f(m);              // pure-VALU 64-lane reduce
                float ss = __expf(x.x - m) + __expf(x.y - m) +
                           __expf(x.z - m) + __expf(x.w - m);
                ss = wave_sum_f(ss);
                if (t < Tbb) acc += m + logf(ss);
                if (!more) break;
                r = rn; t += ts;
            }
        }
        if (l == 0) partial[w] = acc;
    }
}

__global__ __launch_bounds__(64) void ctc_final(
    const float* __restrict__ partial,     // [nW]
    const float* __restrict__ lnterm,      // [B]
    float* __restrict__ out, int B, int nW)
{
    const int b = threadIdx.x;
    float v = 0.f;
    if (b < B) {
        float c = 0.f;
        for (int k = b; k < nW; k += B) c += partial[k];
        v = c - lnterm[b];
    }
    #pragma unroll
    for (int o = 32; o >= 1; o >>= 1) v += __shfl_xor(v, o, 64);
    if (threadIdx.x == 0) out[0] = v / (float)B;
}

extern "C" void kernel_launch(void* const* d_in, const int* in_sizes, int n_in,
                              void* d_out, int out_size, void* d_ws, size_t ws_size,
                              hipStream_t stream) {
    const int*   labels    = (const int*)d_in[0];
    const float* logits    = (const float*)d_in[1];
    const int*   label_len = (const int*)d_in[2];
    const int*   logit_len = (const int*)d_in[3];

    const int B = in_sizes[2];                 // 64
    const int L = in_sizes[0] / B;             // 256
    const int T = in_sizes[1] / (B * V);       // 1024

    const int nLse = 1024;                     // 64 rows per lse wave; %B==0
    float* partial = (float*)d_ws;             // [nLse]
    float* lnterm  = partial + nLse;           // [B]

    ctc_main<<<B + nLse, 64, 0, stream>>>(labels, logits, label_len, logit_len,
                                          partial, lnterm, T, B, L);
    ctc_final<<<1, 64, 0, stream>>>(partial, lnterm, (float*)d_out, B, nLse);
}

// Round 4
// 165.195 us; speedup vs baseline: 1.4770x; 1.2756x over previous
//
#include <hip/hip_runtime.h>
#include <math.h>

// CTC loss, T=1024 B=64 V=256 L=256 (S=513).
// Round 10 = round 9 with the PROC macro-hygiene bug fixed (parameter was
// named `x`, which the preprocessor also substituted into the `.x` member
// tokens -> `_e.ca`). Design unchanged:
// Producer/consumer wave specialization. One 512-thread block per batch
// element: wave 0 (consumer) runs ONLY the 11-op recurrence, eating
// pre-gathered rows; waves 1..7 (producers) load rows, exp them, and gather
// each row into gbuf[half][slot][lane][4] (+ blank scalar bbuf) one window
// ahead. Consumer step = ds_read_b128 (literal offset, conflict-free) +
// broadcast ds_read_b32 + MACS. Window = 16 rows, double-buffered halves,
// one raw "s_waitcnt lgkmcnt(0); s_barrier" per window (vmcnt NOT drained ->
// producers' next-window global loads stay in flight across the barrier).
// Numerics BIT-IDENTICAL to the round-8 kernel (absmax 0.0): same __expf on
// same row values, same gather indices, same MACS order, same renorm points
// (after t=15,31,...), same init/tail, same lse partition (1024 lse waves).
//  - lane l holds states 8l..8l+7; state 512 rides curT, valid on lane 63.
//  - LINEAR-domain recursion on RAW logits (softmax denom deferred to lse).
//  - Renorm every 16 steps; pure-VALU DPP+permlane reduces (no DS).

constexpr int V = 256;
constexpr float LN2_F = 0.6931471805599453f;

typedef unsigned uint2v __attribute__((ext_vector_type(2)));

template <int CTRL>
__device__ __forceinline__ float dpp_mov_f(float x) {
    return __int_as_float(__builtin_amdgcn_update_dpp(
        0, __float_as_int(x), CTRL, 0xF, 0xF, true));
}

// whole-wave shift down by 1 lane (lane l reads lane l-1; lane 0 -> 0). VALU.
__device__ __forceinline__ float wave_shr1_f(float x) {
    return __int_as_float(__builtin_amdgcn_update_dpp(
        0, __float_as_int(x), 0x138, 0xF, 0xF, true));  // wave_shr:1
}

__device__ __forceinline__ float wave_max_f(float m) {
    m = fmaxf(m, dpp_mov_f<0xB1>(m));    // quad_perm xor1
    m = fmaxf(m, dpp_mov_f<0x4E>(m));    // quad_perm xor2
    m = fmaxf(m, dpp_mov_f<0x124>(m));   // row_ror:4
    m = fmaxf(m, dpp_mov_f<0x128>(m));   // row_ror:8
#if __has_builtin(__builtin_amdgcn_permlane16_swap) && __has_builtin(__builtin_amdgcn_permlane32_swap)
    uint2v a = __builtin_amdgcn_permlane16_swap(__float_as_uint(m),
                                                __float_as_uint(m), false, false);
    m = fmaxf(__uint_as_float(a.x), __uint_as_float(a.y));
    uint2v b = __builtin_amdgcn_permlane32_swap(__float_as_uint(m),
                                                __float_as_uint(m), false, false);
    m = fmaxf(__uint_as_float(b.x), __uint_as_float(b.y));
#else
    m = fmaxf(m, __shfl_xor(m, 16, 64));
    m = fmaxf(m, __shfl_xor(m, 32, 64));
#endif
    return m;
}

__device__ __forceinline__ float wave_sum_f(float s) {
    s += dpp_mov_f<0xB1>(s);
    s += dpp_mov_f<0x4E>(s);
    s += dpp_mov_f<0x124>(s);
    s += dpp_mov_f<0x128>(s);
#if __has_builtin(__builtin_amdgcn_permlane16_swap) && __has_builtin(__builtin_amdgcn_permlane32_swap)
    uint2v a = __builtin_amdgcn_permlane16_swap(__float_as_uint(s),
                                                __float_as_uint(s), false, false);
    s = __uint_as_float(a.x) + __uint_as_float(a.y);
    uint2v b = __builtin_amdgcn_permlane32_swap(__float_as_uint(s),
                                                __float_as_uint(s), false, false);
    s = __uint_as_float(b.x) + __uint_as_float(b.y);
#else
    s += __shfl_xor(s, 16, 64);
    s += __shfl_xor(s, 32, 64);
#endif
    return s;
}

#define MACS(EB, E1, E3, E5, E7) do {                                  \
    const float c7m = wave_shr1_f(cur7);                               \
    curT = (curT + cur7) * (EB);                                       \
    cur7 = fmaf(sk7, cur5, cur7 + cur6) * (E7);                        \
    cur6 = (cur6 + cur5) * (EB);                                       \
    cur5 = fmaf(sk5, cur3, cur5 + cur4) * (E5);                        \
    cur4 = (cur4 + cur3) * (EB);                                       \
    cur3 = fmaf(sk3, cur1, cur3 + cur2) * (E3);                        \
    cur2 = (cur2 + cur1) * (EB);                                       \
    cur1 = fmaf(sk1, c7m, cur1 + cur0) * (E1);                         \
    cur0 = (cur0 + c7m) * (EB);                                        \
  } while (0)

#define RENORM do {                                                    \
    curT *= mkT; cur0 *= mk0; cur1 *= mk1; cur2 *= mk2; cur3 *= mk3;   \
    cur4 *= mk4; cur5 *= mk5; cur6 *= mk6; cur7 *= mk7;                \
    float _m = fmaxf(curT, cur0); _m = fmaxf(_m, cur1);                \
    _m = fmaxf(_m, cur2); _m = fmaxf(_m, cur3); _m = fmaxf(_m, cur4);  \
    _m = fmaxf(_m, cur5); _m = fmaxf(_m, cur6); _m = fmaxf(_m, cur7);  \
    _m = wave_max_f(_m);                                               \
    const float _inv = 1.f / fmaxf(_m, 1e-30f);                        \
    log2acc -= log2f(_inv);                                            \
    curT *= _inv; cur0 *= _inv; cur1 *= _inv; cur2 *= _inv;            \
    cur3 *= _inv; cur4 *= _inv; cur5 *= _inv; cur6 *= _inv;            \
    cur7 *= _inv;                                                      \
  } while (0)

// consumer: gather-set ring (8 deep). PRE loads slot S into set N.
#define PRE(N, S) do {                                                 \
    G##N = *(const float4*)(&gbuf[h][S][l][0]);                        \
    A##N = bbuf[h][S];                                                 \
  } while (0)
#define STEPR(N, S) do {                                               \
    MACS(A##N, G##N.x, G##N.y, G##N.z, G##N.w);                        \
    PRE(N, S);                                                         \
  } while (0)
#define STEPC(N) MACS(A##N, G##N.x, G##N.y, G##N.z, G##N.w)

// producer: load row (window WV, sub-row J) ; process loaded row into slot i
#define PLOAD(dst, WV, J)                                              \
    dst = *(const float4*)(lg + rs * (size_t)(16 * (WV) + p + 7 * (J)) + 4 * l)
#define PROC(XV, i) do {                                               \
    float4 _e;                                                         \
    _e.x = __expf((XV).x); _e.y = __expf((XV).y);                      \
    _e.z = __expf((XV).z); _e.w = __expf((XV).w);                      \
    *(float4*)&prow[p][4 * l] = _e;                                    \
    const float* _pr = prow[p];                                        \
    float _gb = _pr[0];                                                \
    float4 _gv;                                                        \
    _gv.x = _pr[ix]; _gv.y = _pr[iy]; _gv.z = _pr[iz]; _gv.w = _pr[iw];\
    *(float4*)&gbuf[h][i][l][0] = _gv;                                 \
    if (l == 0) bbuf[h][i] = _gb;                                      \
  } while (0)

#define WG_BARRIER asm volatile("s_waitcnt lgkmcnt(0)\n\ts_barrier" ::: "memory")

__global__ __launch_bounds__(512) void ctc_main(
    const int*   __restrict__ labels,      // [B, L]
    const float* __restrict__ logits,      // [T, B, V]
    const int*   __restrict__ label_len,   // [B]
    const int*   __restrict__ logit_len,   // [B]
    float*       __restrict__ partial,     // [nLse] per-wave lse sums
    float*       __restrict__ lnterm,      // [B]
    int T, int B, int L)
{
    const int tid = threadIdx.x;
    const int wid = tid >> 6;              // wave 0 = consumer, 1..7 producers
    const int l   = tid & 63;

    if ((int)blockIdx.x < B) {
        // =============== recursion block: one batch element ==================
        __shared__ __align__(16) float gbuf[2][16][64][4];  // gathered rows
        __shared__ float bbuf[2][16];                       // blank per row
        __shared__ __align__(16) float prow[7][256];        // producer scratch
        __shared__ float afin[514];

        const int b = blockIdx.x;
        const int Tb = logit_len[b];
        const int Lb = label_len[b];
        const int Sb = 2 * Lb + 1;

        const float* lg = logits + (size_t)b * V;
        const size_t rs = (size_t)B * V;

        const int4 lb4 = ((const int4*)(labels + (size_t)b * L))[l];
        const int ix = lb4.x, iy = lb4.y, iz = lb4.z, iw = lb4.w;
        const int prevw = __shfl_up(iw, 1);
        const float sk1 = (l > 0 && ix != prevw) ? 1.f : 0.f;
        const float sk3 = (iy != ix) ? 1.f : 0.f;
        const float sk5 = (iz != iy) ? 1.f : 0.f;
        const float sk7 = (iw != iz) ? 1.f : 0.f;

        const float mk0 = (8 * l + 0 < Sb) ? 1.f : 0.f;
        const float mk1 = (8 * l + 1 < Sb) ? 1.f : 0.f;
        const float mk2 = (8 * l + 2 < Sb) ? 1.f : 0.f;
        const float mk3 = (8 * l + 3 < Sb) ? 1.f : 0.f;
        const float mk4 = (8 * l + 4 < Sb) ? 1.f : 0.f;
        const float mk5 = (8 * l + 5 < Sb) ? 1.f : 0.f;
        const float mk6 = (8 * l + 6 < Sb) ? 1.f : 0.f;
        const float mk7 = (8 * l + 7 < Sb) ? 1.f : 0.f;
        const float mkT = (Sb > 512 && l == 63) ? 1.f : 0.f;

        // t=0 init (identical to round-8): states 0,1 only, lane 0
        float cur0 = 0.f, cur1 = 0.f, cur2 = 0.f, cur3 = 0.f;
        float cur4 = 0.f, cur5 = 0.f, cur6 = 0.f, cur7 = 0.f, curT = 0.f;
        if (l == 0) {
            cur0 = __expf(lg[0]);
            cur1 = __expf(lg[ix]) * mk1;
        }
        float log2acc = 0.f;

        // windows: window w = rows 16w..16w+15 (row 0 staged but unused).
        // consumer eats slots 1..15 in window 0, 0..15 otherwise; renorm after
        // each window -> renorm points t=15,31,... exactly as round-8.
        const int NW = Tb / 16;

        float4 G0{}, G1{}, G2{}, G3{}, G4{}, G5{}, G6{}, G7{};
        float  A0 = 0, A1 = 0, A2 = 0, A3 = 0, A4 = 0, A5 = 0, A6 = 0, A7 = 0;

        // producer state
        const int p = (wid > 0) ? wid - 1 : 0;     // 0..6
        const bool three = (p < 2);                // waves 1,2 take 3 rows
        float4 ca{}, cb{}, cc{}, na{}, nb{}, nc{};
        if (wid > 0 && NW > 0) {
            PLOAD(ca, 0, 0);
            PLOAD(cb, 0, 1);
            if (three) PLOAD(cc, 0, 2);
        }
        if (wid == 0) __builtin_amdgcn_s_setprio(1);

        for (int k = 0; k <= NW; ++k) {
            if (wid != 0) {
                if (k < NW) {
                    const int h = k & 1;
                    if (k + 1 < NW) {
                        PLOAD(na, k + 1, 0);
                        PLOAD(nb, k + 1, 1);
                        if (three) PLOAD(nc, k + 1, 2);
                    }
                    PROC(ca, p);
                    PROC(cb, p + 7);
                    if (three) PROC(cc, p + 14);
                    ca = na; cb = nb; cc = nc;
                }
            } else if (k >= 1) {
                const int w = k - 1;
                const int h = w & 1;
                if (w == 0) {
                    PRE(1, 1); PRE(2, 2); PRE(3, 3); PRE(4, 4);
                    PRE(5, 5); PRE(6, 6); PRE(7, 7); PRE(0, 8);
                    STEPR(1, 9);  STEPR(2, 10); STEPR(3, 11); STEPR(4, 12);
                    STEPR(5, 13); STEPR(6, 14); STEPR(7, 15);
                    STEPC(0);
                    STEPC(1); STEPC(2); STEPC(3); STEPC(4);
                    STEPC(5); STEPC(6); STEPC(7);
                } else {
                    PRE(0, 0); PRE(1, 1); PRE(2, 2); PRE(3, 3);
                    PRE(4, 4); PRE(5, 5); PRE(6, 6); PRE(7, 7);
                    STEPR(0, 8);  STEPR(1, 9);  STEPR(2, 10); STEPR(3, 11);
                    STEPR(4, 12); STEPR(5, 13); STEPR(6, 14); STEPR(7, 15);
                    STEPC(0); STEPC(1); STEPC(2); STEPC(3);
                    STEPC(4); STEPC(5); STEPC(6); STEPC(7);
                }
                RENORM;
            }
            WG_BARRIER;
        }

        if (wid == 0) {
            // scalar tail (t = 16*NW..Tb-1), identical numerics to round-8
            for (int t = 16 * NW; t < Tb; ++t) {
                if (t < 1) continue;               // (Tb<16 edge: t starts 0)
                const float* rowp = lg + rs * (size_t)t;
                const float eb = __expf(rowp[0]);
                const float e1 = __expf(rowp[ix]), e3 = __expf(rowp[iy]);
                const float e5 = __expf(rowp[iz]), e7 = __expf(rowp[iw]);
                MACS(eb, e1, e3, e5, e7);
            }

            afin[8 * l + 0] = cur0; afin[8 * l + 1] = cur1;
            afin[8 * l + 2] = cur2; afin[8 * l + 3] = cur3;
            afin[8 * l + 4] = cur4; afin[8 * l + 5] = cur5;
            afin[8 * l + 6] = cur6; afin[8 * l + 7] = cur7;
            if (l == 63) afin[512] = curT;
            const int end = 2 * Lb;
            const int em1 = (end > 0) ? end - 1 : 0;
            float ssum = afin[end] + afin[em1];     // same-wave DS, in-order
            ssum = fmaxf(ssum, 1e-37f);
            if (l == 0) lnterm[b] = logf(ssum) + LN2_F * log2acc;
        }
    } else {
        // ====== lse: 8 waves/block, wave handles w = (bid-B)*8 + wid =========
        const int w  = ((int)blockIdx.x - B) * 8 + wid;
        const int nW = ((int)gridDim.x - B) * 8;
        const int rows = T * B;
        const int bb = w % B;
        const int Tbb = logit_len[bb];
        float acc = 0.f;
        int r = w;
        if (r < rows) {
            int t = w / B;
            const int ts = nW / B;
            float4 nxt = ((const float4*)(logits + (size_t)r * V))[l];
            while (true) {
                const int rn = r + nW;
                const bool more = rn < rows;
                const float4 x = nxt;
                if (more) nxt = ((const float4*)(logits + (size_t)rn * V))[l];
                float m = fmaxf(fmaxf(x.x, x.y), fmaxf(x.z, x.w));
                m = wave_max_f(m);
                float ss = __expf(x.x - m) + __expf(x.y - m) +
                           __expf(x.z - m) + __expf(x.w - m);
                ss = wave_sum_f(ss);
                if (t < Tbb) acc += m + logf(ss);
                if (!more) break;
                r = rn; t += ts;
            }
        }
        if (l == 0) partial[w] = acc;
    }
}

__global__ __launch_bounds__(64) void ctc_final(
    const float* __restrict__ partial,     // [nW]
    const float* __restrict__ lnterm,      // [B]
    float* __restrict__ out, int B, int nW)
{
    const int b = threadIdx.x;
    float v = 0.f;
    if (b < B) {
        float c = 0.f;
        for (int k = b; k < nW; k += B) c += partial[k];
        v = c - lnterm[b];
    }
    #pragma unroll
    for (int o = 32; o >= 1; o >>= 1) v += __shfl_xor(v, o, 64);
    if (threadIdx.x == 0) out[0] = v / (float)B;
}

extern "C" void kernel_launch(void* const* d_in, const int* in_sizes, int n_in,
                              void* d_out, int out_size, void* d_ws, size_t ws_size,
                              hipStream_t stream) {
    const int*   labels    = (const int*)d_in[0];
    const float* logits    = (const float*)d_in[1];
    const int*   label_len = (const int*)d_in[2];
    const int*   logit_len = (const int*)d_in[3];

    const int B = in_sizes[2];                 // 64
    const int L = in_sizes[0] / B;             // 256
    const int T = in_sizes[1] / (B * V);       // 1024

    const int nLse = 1024;                     // 8 lse waves per lse block
    float* partial = (float*)d_ws;             // [nLse]
    float* lnterm  = partial + nLse;           // [B]

    ctc_main<<<B + nLse / 8, 512, 0, stream>>>(labels, logits, label_len,
                                               logit_len, partial, lnterm,
                                               T, B, L);
    ctc_final<<<1, 64, 0, stream>>>(partial, lnterm, (float*)d_out, B, nLse);
}